// Round 10
// baseline (409.855 us; speedup 1.0000x reference)
//
#include <hip/hip_runtime.h>
#include <math.h>

// SVDObserver: x (64,512,64,64) f32, w_proj (24,512) f32, ema_s (24) f32
// outputs (flat f32 concat): S (64,24) | Vh (64,24,24) | features (64,50) | novelty (64,24)
//
//  K1 proj_gram: 512 blocks x 128 thr x 4 px (2 blocks/CU). 4 px/thread
//     quarters the broadcast W ds_read count (DS-pipe was the r8/r9 K1
//     bottleneck: 8 waves x 3072 x 12cyc = 137us model vs 147 measured).
//     Wave = 256 px = one Gram tile (16/batch), staged in 4 rounds of 64 px.
//  K3 eigh_feat: frozen from r9 (rsq-slartg, fused Z rotations, stride-65
//     unguarded Zl, ballot scans, reduce sort). Prologue now sums 16 partials.

#define N24 24
#define ZST 65  // Zl row stride: >=64 (rows 24-63 inert), odd (bank-friendly)
#define HS 25   // h staging pixel stride in K1

// ---------------------------------------------------------------- K1
__global__ __launch_bounds__(128, 1) void proj_gram_kernel(
    const float* __restrict__ x, const float* __restrict__ w,
    double* __restrict__ partial)
{
    const int b    = blockIdx.x >> 3;
    const int q    = blockIdx.x & 7;
    const int tid  = threadIdx.x;
    const int wv   = tid >> 6;
    const int lane = tid & 63;
    const int n0   = (q << 9) | (tid << 2);        // 4 consecutive pixels
    __shared__ __align__(16) float wl[24 * 512];   // 48 KB
    __shared__ float hq[2][64 * HS];               // 2 x 6.4 KB wave round-buffers
    for (int i2 = tid; i2 < 24 * 512; i2 += 128) wl[i2] = w[i2];
    __syncthreads();                               // the ONLY barrier

    const float* xb = x + ((size_t)b << 21) + n0;  // b*512*4096 + n0
    float h[4][24];
#pragma unroll
    for (int j = 0; j < 4; ++j)
#pragma unroll
        for (int k = 0; k < 24; ++k) h[j][k] = 0.f;

    float4 cA[8];
#pragma unroll
    for (int t = 0; t < 8; ++t)
        cA[t] = *reinterpret_cast<const float4*>(xb + ((size_t)t << 12));

    for (int c = 0; c < 512; c += 8) {
        float4 cB[8];
        if (c + 8 < 512) {
#pragma unroll
            for (int t = 0; t < 8; ++t)
                cB[t] = *reinterpret_cast<const float4*>(xb + ((size_t)(c + 8 + t) << 12));
        }
#pragma unroll
        for (int sub = 0; sub < 2; ++sub) {
            const float4 a0 = cA[sub * 4 + 0];
            const float4 a1 = cA[sub * 4 + 1];
            const float4 a2 = cA[sub * 4 + 2];
            const float4 a3 = cA[sub * 4 + 3];
            const int cc = c + sub * 4;
#pragma unroll
            for (int k = 0; k < 24; ++k) {
                const float4 wv4 = *reinterpret_cast<const float4*>(&wl[k * 512 + cc]);
                h[0][k] += wv4.x * a0.x + wv4.y * a1.x + wv4.z * a2.x + wv4.w * a3.x;
                h[1][k] += wv4.x * a0.y + wv4.y * a1.y + wv4.z * a2.y + wv4.w * a3.y;
                h[2][k] += wv4.x * a0.z + wv4.y * a1.z + wv4.z * a2.z + wv4.w * a3.z;
                h[3][k] += wv4.x * a0.w + wv4.y * a1.w + wv4.z * a2.w + wv4.w * a3.w;
            }
        }
#pragma unroll
        for (int t = 0; t < 8; ++t) cA[t] = cB[t];
    }

    // wave-private Gram over this wave's 256 px (tile = q*2+wv), 4 rounds of 64 px
    float* hr = hq[wv];
    int pk[5], pm[5];
#pragma unroll
    for (int u = 0; u < 5; ++u) {
        int p = lane + u * 64;
        int k = 0, pp = p;
        if (p < 300) {
            while (pp >= 24 - k) { pp -= 24 - k; ++k; }
        }
        pk[u] = k; pm[u] = k + pp;
    }
    double acc[5];
#pragma unroll
    for (int u = 0; u < 5; ++u) acc[u] = 0.0;

    for (int r = 0; r < 4; ++r) {
        if ((lane >> 4) == r) {                    // lanes 16r..16r+15 stage their 4 px
            int base = lane - (r << 4);            // 0..15
#pragma unroll
            for (int j = 0; j < 4; ++j)
#pragma unroll
                for (int k = 0; k < 24; ++k)
                    hr[((base << 2) + j) * HS + k] = h[j][k];
        }
        __builtin_amdgcn_wave_barrier();
        // same-wave LDS RAW/WAR: DS pipe per-wave in-order; compiler inserts lgkmcnt
#pragma unroll
        for (int u = 0; u < 5; ++u) {
            if (lane + u * 64 < 300) {
                double a = acc[u];
                for (int i2 = 0; i2 < 64; ++i2)
                    a += (double)hr[i2 * HS + pk[u]] * (double)hr[i2 * HS + pm[u]];
                acc[u] = a;
            }
        }
        __builtin_amdgcn_wave_barrier();
    }
#pragma unroll
    for (int u = 0; u < 5; ++u) {
        int p = lane + u * 64;
        if (p < 300)
            partial[((size_t)(b * 16 + (q << 1) + wv)) * 300 + p] = acc[u];
    }
}

// ------------------------------------------------------- LAPACK helpers
__device__ __forceinline__ float rlf(float v, int l) {
    return __int_as_float(__builtin_amdgcn_readlane(__float_as_int(v), l));
}

__device__ __forceinline__ float lapy2f(float xx, float yy) {
#pragma clang fp contract(off)
    float xa = fabsf(xx), ya = fabsf(yy);
    float w = fmaxf(xa, ya), z = fminf(xa, ya);
    float q = z / w;
    float res = w * sqrtf(1.f + q * q);
    return (z == 0.f) ? w : res;
}

// fast sqrt(g^2+1) via v_rsq (hot path only)
__device__ __forceinline__ float lapy2_1_fast(float g) {
    float t = g * g + 1.f;
    return t * __builtin_amdgcn_rsqf(t);
}

// hot-path slartg: v_rsq core (~1ulp). Sign conventions == LAPACK >=3.10.
__device__ __forceinline__ void slartg_(float f, float g, float& c, float& s, float& r) {
    float f1 = fabsf(f), g1 = fabsf(g);
    const float rtmin_ = 0x1p-63f;
    const float rtmax_ = 1.8446743e+19f;
    bool inr = (f1 > rtmin_) && (f1 < rtmax_) && (g1 > rtmin_) && (g1 < rtmax_);
    if (__builtin_expect(!inr && f != 0.f && g != 0.f, 0)) {
#pragma clang fp contract(off)
        float u = fminf(3.4028235e+38f, fmaxf(0x1p-126f, fmaxf(f1, g1)));
        float fs = f / u, gs = g / u;
        float d = sqrtf(fs * fs + gs * gs);
        float p = 1.f / d;
        c = fabsf(fs) * p;
        s = gs * copysignf(p, f);
        r = copysignf(d, f) * u;
    } else {
        float d2 = f * f + g * g;
        float p = __builtin_amdgcn_rsqf(d2);
        float cN = f1 * p;
        float sN = g * copysignf(p, f);
        float rN = copysignf(d2 * p, f);
        bool gz = (g == 0.f);
        c = gz ? 1.f : cN;
        s = gz ? 0.f : sN;
        r = gz ? f : rN;
    }
}

__device__ __forceinline__ void slaev2_(float a, float b, float cc,
                                        float& rt1, float& rt2, float& cs1, float& sn1) {
#pragma clang fp contract(off)
    float sm = a + cc, df = a - cc, adf = fabsf(df);
    float tb = b + b, ab = fabsf(tb);
    float acmx, acmn;
    if (fabsf(a) > fabsf(cc)) { acmx = a; acmn = cc; } else { acmx = cc; acmn = a; }
    float rt;
    if (adf > ab)      { float q = ab / adf; rt = adf * sqrtf(1.f + q * q); }
    else if (adf < ab) { float q = adf / ab; rt = ab * sqrtf(1.f + q * q); }
    else               rt = ab * sqrtf(2.f);
    int sgn1;
    if (sm < 0.f)      { rt1 = 0.5f * (sm - rt); sgn1 = -1; rt2 = (acmx / rt1) * acmn - (b / rt1) * b; }
    else if (sm > 0.f) { rt1 = 0.5f * (sm + rt); sgn1 =  1; rt2 = (acmx / rt1) * acmn - (b / rt1) * b; }
    else               { rt1 = 0.5f * rt; rt2 = -0.5f * rt; sgn1 = 1; }
    float cs; int sgn2;
    if (df >= 0.f) { cs = df + rt; sgn2 = 1; } else { cs = df - rt; sgn2 = -1; }
    float acs = fabsf(cs);
    if (acs > ab) { float ct = -tb / cs; sn1 = 1.f / sqrtf(1.f + ct * ct); cs1 = ct * sn1; }
    else {
        if (ab == 0.f) { cs1 = 1.f; sn1 = 0.f; }
        else { float tn = -cs / tb; cs1 = 1.f / sqrtf(1.f + tn * tn); sn1 = tn * cs1; }
    }
    if (sgn1 == sgn2) { float tn = cs1; cs1 = -sn1; sn1 = tn; }
}

#define RD(j)   rlf(dr, (j) - 1)
#define RE(j)   rlf(er, (j) - 1)
#define WD(j,v) { float _v = (v); int _j = (j) - 1; dr = (lane == _j) ? _v : dr; }
#define WE(j,v) { float _v = (v); int _j = (j) - 1; er = (lane == _j) ? _v : er; }

// ---------------------------------------------------------------- K3 merged
__global__ __launch_bounds__(64) void eigh_feat_kernel(
    const double* __restrict__ partial, const float* __restrict__ ema,
    float* __restrict__ out)
{
#pragma clang fp contract(off)
    const int b = blockIdx.x;
    const int lane = threadIdx.x;
    const int n = N24;

    __shared__ float A[N24 * N24];      // col-major A[i + 24*j]
    __shared__ float Zl[ZST * N24];     // row r (0..63 incl. padding), col j at Zl[r + ZST*j]
    __shared__ float dl[N24 + 1], el[N24 + 1], tau[N24 + 1];
    __shared__ float hv[N24], hw[N24];
    __shared__ float Sarr[N24], snorm[N24];

    // ---------- G reduce prologue: 16 fp64 partials, serial t order ----------
    for (int p = lane; p < 300; p += 64) {
        int k = 0, pp = p;
        while (pp >= 24 - k) { pp -= 24 - k; ++k; }
        int m = k + pp;
        double acc = 0.0;
        for (int t = 0; t < 16; ++t)
            acc += partial[((size_t)(b * 16 + t)) * 300 + p];
        float v = (float)acc;
        A[k + N24 * m] = v;
        A[m + N24 * k] = v;
    }
    __syncthreads();

    // ---------- ssytd2 (lower) ----------
    for (int i = 0; i < n - 1; ++i) {
        const int mlen = n - 1 - i;
        float alpha = A[(i + 1) + N24 * i];
        float ss = 0.f;
        for (int r = i + 2; r < n; ++r) { float t = A[r + N24 * i]; ss += t * t; }
        float xnorm = sqrtf(ss);
        if (xnorm == 0.f) {
            if (lane == 0) { tau[i + 1] = 0.f; el[i + 1] = alpha; dl[i + 1] = A[i + N24 * i]; }
            __syncthreads();
            continue;
        }
        float beta = -copysignf(lapy2f(alpha, xnorm), alpha);
        float taui = (beta - alpha) / beta;
        float scal = 1.f / (alpha - beta);
        if (lane == 0) { tau[i + 1] = taui; el[i + 1] = beta; }
        __syncthreads();
        if (lane >= i + 2 && lane < n) A[lane + N24 * i] *= scal;
        __syncthreads();
        if (lane < mlen) hv[lane] = (lane == 0) ? 1.f : A[(i + 1 + lane) + N24 * i];
        __syncthreads();
        if (lane < mlen) {                      // x = tau * Asub * v
            float acc = 0.f;
            int gr = i + 1 + lane;
            for (int c2 = 0; c2 < mlen; ++c2) {
                int gc = i + 1 + c2;
                float av = (gr >= gc) ? A[gr + N24 * gc] : A[gc + N24 * gr];
                acc += av * hv[c2];
            }
            hw[lane] = taui * acc;
        }
        __syncthreads();
        float dot = 0.f;
        for (int r2 = 0; r2 < mlen; ++r2) dot += hw[r2] * hv[r2];
        float alpha2 = -0.5f * taui * dot;
        __syncthreads();
        if (lane < mlen) hw[lane] += alpha2 * hv[lane];
        __syncthreads();
        if (lane < mlen) {                      // rank-2 update, lower triangle
            for (int c2 = 0; c2 <= lane; ++c2)
                A[(i + 1 + lane) + N24 * (i + 1 + c2)] -= hv[lane] * hw[c2] + hw[lane] * hv[c2];
        }
        __syncthreads();
        if (lane == 0) dl[i + 1] = A[i + N24 * i];
        __syncthreads();
    }
    if (lane == 0) dl[n] = A[(n - 1) + N24 * (n - 1)];
    __syncthreads();

    // ---------- ssteqr('I'), Zl rows 24-63 are inert padding ----------
#pragma unroll
    for (int j = 0; j < N24; ++j) Zl[lane + ZST * j] = (lane == j) ? 1.f : 0.f;

    float dr = (lane < 24) ? dl[lane + 1] : 0.f;
    float er = (lane < 23) ? el[lane + 1] : 0.f;

    {
        const float eps_    = 0x1p-24f;
        const float eps2_   = 0x1p-48f;
        const float safmin_ = 0x1p-126f;
        const float ssfmax_ = 3.0744573e+18f;
        const float ssfmin_ = 0x1p-15f;
        const int nmaxit = n * 30;
        int jtot = 0, l1 = 1;
        int l = 0, lsv = 0, lend = 0, lendsv = 0, mb = 0, iscale = 0;
        float anorm = 0.f, p = 0.f, g = 0.f, r_ = 0.f, c_ = 0.f, s_ = 0.f, f_ = 0.f, b_ = 0.f;
        float rt1 = 0.f, rt2 = 0.f, cc = 0.f, sn = 0.f;
        int m_ = 0, i_ = 0;

L10:
        if (l1 > n) goto L160;
        if (l1 > 1) WE(l1 - 1, 0.f);
        {   // ballot deflation scan over m in [l1, n-1]
            float dnx = __shfl_down(dr, 1, 64);
            float ae = fabsf(er);
            bool inr = (lane >= l1 - 1) && (lane <= n - 2);
            bool t0 = inr && (ae == 0.f);
            bool t1 = inr && (ae <= (sqrtf(fabsf(dr)) * sqrtf(fabsf(dnx))) * eps_);
            unsigned long long msk0 = __ballot(t0);
            unsigned long long mskc = msk0 | __ballot(t1);
            if (mskc) {
                int bit = __builtin_ctzll(mskc);
                m_ = bit + 1;
                bool wasz = (msk0 >> bit) & 1ull;
                if (!wasz) WE(m_, 0.f);
            } else m_ = n;
        }
        l = l1; lsv = l; lend = m_; lendsv = lend; l1 = m_ + 1;
        if (lend == l) goto L10;

        {   // anorm (exact fmax reduce)
            bool ind = (lane >= l - 1) && (lane <= lend - 1);
            bool ine = (lane >= l - 1) && (lane <= lend - 2);
            float v = fmaxf(ind ? fabsf(dr) : 0.f, ine ? fabsf(er) : 0.f);
            for (int off = 32; off; off >>= 1) v = fmaxf(v, __shfl_xor(v, off, 64));
            anorm = v;
        }
        iscale = 0;
        if (anorm == 0.f) goto L10;
        if (anorm > ssfmax_) {
            iscale = 1;
            float mul = ssfmax_ / anorm;
            if (lane + 1 >= l && lane + 1 <= lend) dr *= mul;
            if (lane + 1 >= l && lane + 1 <= lend - 1) er *= mul;
        } else if (anorm < ssfmin_) {
            iscale = 2;
            float mul = ssfmin_ / anorm;
            if (lane + 1 >= l && lane + 1 <= lend) dr *= mul;
            if (lane + 1 >= l && lane + 1 <= lend - 1) er *= mul;
        }
        if (fabsf(RD(lend)) < fabsf(RD(l))) { lend = lsv; l = lendsv; }

        if (lend > l) {
            // ------------- QL -------------
L40:
            if (l != lend) {
                float dnx = __shfl_down(dr, 1, 64);
                bool inr = (lane >= l - 1) && (lane <= lend - 2);
                bool t = inr && (er * er <= (eps2_ * fabsf(dr)) * fabsf(dnx) + safmin_);
                unsigned long long msk = __ballot(t);
                m_ = msk ? (__builtin_ctzll(msk) + 1) : lend;
            } else m_ = lend;
            if (m_ < lend) WE(m_, 0.f);
            mb = m_;
            p = RD(l);
            if (mb == l) goto L80;
            if (mb == l + 1) {                      // 2x2 (unguarded: rows 24-63 inert)
                slaev2_(RD(l), RE(l), RD(l + 1), rt1, rt2, cc, sn);
                {
                    float z1 = Zl[lane + ZST * l];
                    float z0 = Zl[lane + ZST * (l - 1)];
                    Zl[lane + ZST * l]       = cc * z1 - sn * z0;
                    Zl[lane + ZST * (l - 1)] = sn * z1 + cc * z0;
                }
                WD(l, rt1); WD(l + 1, rt2); WE(l, 0.f);
                l = l + 2;
                if (l <= lend) goto L40;
                goto L140;
            }
            if (jtot == nmaxit) goto L140;
            jtot = jtot + 1;
            {
                float dmb = RD(mb);
                float el_ = RE(l);
                g = (RD(l + 1) - p) * __builtin_amdgcn_rcpf(2.f * el_);
                r_ = lapy2_1_fast(g);
                g = dmb - p + el_ * __builtin_amdgcn_rcpf(g + copysignf(r_, g));
                s_ = 1.f; c_ = 1.f; p = 0.f;
                float dcar = dmb;                   // d[i_+1] carry
                float carry = Zl[lane + ZST * (mb - 1)];
                for (i_ = mb - 1; i_ >= l; --i_) {
                    float prev = Zl[lane + ZST * (i_ - 1)];   // hoisted LDS read
                    float ei = RE(i_);
                    float di = RD(i_);
                    f_ = s_ * ei;
                    b_ = c_ * ei;
                    slartg_(g, f_, c_, s_, r_);
                    er = ((i_ != mb - 1) && (lane == i_)) ? r_ : er;   // WE(i_+1)
                    g = dcar - p;
                    r_ = (di - g) * s_ + 2.f * c_ * b_;
                    p = s_ * r_;
                    dr = (lane == i_) ? (g + p) : dr;                  // WD(i_+1)
                    g = c_ * r_ - b_;
                    dcar = di;
                    // fused dlasr 'R','V','B' step: cj = c_, sj = -s_
                    float sj = -s_;
                    Zl[lane + ZST * i_] = c_ * carry - sj * prev;
                    carry = sj * carry + c_ * prev;
                }
                Zl[lane + ZST * (l - 1)] = carry;
                WD(l, dcar - p);
                WE(l, g);
            }
            goto L40;
L80:
            WD(l, p);
            l = l + 1;
            if (l <= lend) goto L40;
            goto L140;
        } else {
            // ------------- QR -------------
L90:
            if (l != lend) {
                float epu = __shfl_up(er, 1, 64);
                float dup = __shfl_up(dr, 1, 64);
                bool inr = (lane >= lend) && (lane <= l - 1);
                bool t = inr && (epu * epu <= (eps2_ * fabsf(dr)) * fabsf(dup) + safmin_);
                unsigned long long msk = __ballot(t);
                if (msk) {
                    m_ = 63 - __builtin_clzll(msk) + 1;
                } else m_ = lend;
            } else m_ = lend;
            if (m_ > lend) WE(m_ - 1, 0.f);
            mb = m_;
            p = RD(l);
            if (mb == l) goto L130;
            if (mb == l - 1) {                      // 2x2 (unguarded)
                slaev2_(RD(l - 1), RE(l - 1), RD(l), rt1, rt2, cc, sn);
                {
                    float z1 = Zl[lane + ZST * (l - 1)];
                    float z0 = Zl[lane + ZST * (l - 2)];
                    Zl[lane + ZST * (l - 1)] = cc * z1 - sn * z0;
                    Zl[lane + ZST * (l - 2)] = sn * z1 + cc * z0;
                }
                WD(l - 1, rt1); WD(l, rt2); WE(l - 1, 0.f);
                l = l - 2;
                if (l >= lend) goto L90;
                goto L140;
            }
            if (jtot == nmaxit) goto L140;
            jtot = jtot + 1;
            {
                float dmb = RD(mb);
                float el1 = RE(l - 1);
                g = (RD(l - 1) - p) * __builtin_amdgcn_rcpf(2.f * el1);
                r_ = lapy2_1_fast(g);
                g = dmb - p + el1 * __builtin_amdgcn_rcpf(g + copysignf(r_, g));
                s_ = 1.f; c_ = 1.f; p = 0.f;
                float dcar = dmb;                   // d[i_] carry
                float carryPrev = Zl[lane + ZST * (mb - 1)];
                for (i_ = mb; i_ <= l - 1; ++i_) {
                    float t = Zl[lane + ZST * i_];            // hoisted LDS read
                    float ei = RE(i_);
                    float dnx = RD(i_ + 1);
                    f_ = s_ * ei;
                    b_ = c_ * ei;
                    slartg_(g, f_, c_, s_, r_);
                    er = ((i_ != mb) && (lane == i_ - 2)) ? r_ : er;   // WE(i_-1)
                    g = dcar - p;
                    r_ = (dnx - g) * s_ + 2.f * c_ * b_;
                    p = s_ * r_;
                    dr = (lane == i_ - 1) ? (g + p) : dr;              // WD(i_)
                    g = c_ * r_ - b_;
                    dcar = dnx;
                    // fused dlasr 'R','V','F' step: cj = c_, sj = s_
                    Zl[lane + ZST * (i_ - 1)] = s_ * t + c_ * carryPrev;
                    carryPrev = c_ * t - s_ * carryPrev;
                }
                Zl[lane + ZST * (l - 1)] = carryPrev;
                WD(l, dcar - p);
                WE(l - 1, g);
            }
            goto L90;
L130:
            WD(l, p);
            l = l - 1;
            if (l >= lend) goto L90;
            goto L140;
        }
L140:
        if (iscale == 1) {
            float mul = anorm / ssfmax_;
            if (lane + 1 >= lsv && lane + 1 <= lendsv) dr *= mul;
            if (lane + 1 >= lsv && lane + 1 <= lendsv - 1) er *= mul;
        } else if (iscale == 2) {
            float mul = anorm / ssfmin_;
            if (lane + 1 >= lsv && lane + 1 <= lendsv) dr *= mul;
            if (lane + 1 >= lsv && lane + 1 <= lendsv - 1) er *= mul;
        }
        if (jtot < nmaxit) goto L10;
        goto L160;

L160:
        // selection sort ascending via min+index reduce (tie -> lowest index)
        for (int ii = 2; ii <= n; ++ii) {
            int ia = ii - 1;
            float val = (lane >= ii - 2 && lane <= n - 1) ? dr : __builtin_inff();
            int idx = lane + 1;
            for (int off = 32; off; off >>= 1) {
                float v2 = __shfl_xor(val, off, 64);
                int   i2 = __shfl_xor(idx, off, 64);
                bool take = (v2 < val) || ((v2 == val) && (i2 < idx));
                val = take ? v2 : val;
                idx = take ? i2 : idx;
            }
            int ka = idx;
            float pp = val;
            if (ka != ia) {
                float dia = RD(ia);
                WD(ka, dia);
                WD(ia, pp);
                {   // unguarded column swap (rows 24-63 inert)
                    float t = Zl[lane + ZST * (ia - 1)];
                    Zl[lane + ZST * (ia - 1)] = Zl[lane + ZST * (ka - 1)];
                    Zl[lane + ZST * (ka - 1)] = t;
                }
            }
        }
    }

    if (lane < 24) dl[lane + 1] = dr;
    __syncthreads();

    // ---------- sormtr: Z := H(1)...H(n-1) * Z  (lane = column) ----------
    for (int i = n - 2; i >= 0; --i) {
        float taui = tau[i + 1];
        if (taui != 0.f && lane < n) {
            int j = lane;
            float w_ = Zl[(i + 1) + ZST * j];
            for (int r = i + 2; r < n; ++r) w_ += A[r + N24 * i] * Zl[r + ZST * j];
            Zl[(i + 1) + ZST * j] -= taui * w_;
            for (int r = i + 2; r < n; ++r) Zl[r + ZST * j] -= taui * (A[r + N24 * i] * w_);
        }
        __syncthreads();
    }

    // ---------- S, Vh, features, novelty ----------
    const int S_OFF = 0, VH_OFF = 1536, F_OFF = 38400, NOV_OFF = 41600;
    if (lane < n) {
        float ev = dl[n - lane];                   // descending
        float s0 = sqrtf(fmaxf(ev, 0.f));
        s0 = fmaxf(s0, 1e-6f);
        if (!isfinite(s0)) s0 = 1.f;
        Sarr[lane] = s0;
    }
    __syncthreads();
    if (lane < n) {
        out[S_OFF + b * 24 + lane] = Sarr[lane];
        out[NOV_OFF + b * 24 + lane] = Sarr[lane] - ema[lane];
    }
    for (int idx = lane; idx < 576; idx += 64) {   // Vh[j][i] = Z[i][23-j]
        int j = idx / 24, i2 = idx % 24;
        float vv = Zl[i2 + ZST * (23 - j)];
        if (!isfinite(vv)) vv = 0.f;
        out[VH_OFF + b * 576 + idx] = vv;
    }
    float sum_ = 0.f;
    for (int j2 = 0; j2 < n; ++j2) sum_ += Sarr[j2];
    float denom = sum_ + 1e-8f;
    if (lane < n) snorm[lane] = Sarr[lane] / denom;
    __syncthreads();
    float ent = 0.f;
    for (int j2 = 0; j2 < n; ++j2) {
        float sn2 = snorm[j2];
        ent -= sn2 * logf(fmaxf(sn2, 1e-8f));
    }
    float sumsq = 0.f, diagsq = 0.f;
    for (int j2 = 0; j2 < n; ++j2)
        for (int i2 = 0; i2 < n; ++i2) { float z = Zl[i2 + ZST * j2]; sumsq += z * z; }
    for (int j2 = 0; j2 < n; ++j2) { float dv = Zl[j2 + ZST * (23 - j2)]; diagsq += dv * dv; }
    float offd = fmaxf(sumsq - diagsq, 0.f);
    if (lane < n) {
        float v0 = snorm[lane]; if (!isfinite(v0)) v0 = 0.f;
        out[F_OFF + b * 50 + lane] = v0;
        float dv = Zl[lane + ZST * (23 - lane)]; if (!isfinite(dv)) dv = 0.f;
        out[F_OFF + b * 50 + 24 + lane] = dv;
    }
    if (lane == 0) {
        if (!isfinite(offd)) offd = 0.f;
        if (!isfinite(ent)) ent = 0.f;
        out[F_OFF + b * 50 + 48] = offd;
        out[F_OFF + b * 50 + 49] = ent;
    }
}

// ---------------------------------------------------------------- launch
extern "C" void kernel_launch(void* const* d_in, const int* in_sizes, int n_in,
                              void* d_out, int out_size, void* d_ws, size_t ws_size,
                              hipStream_t stream)
{
    const float* x   = (const float*)d_in[0];
    const float* w   = (const float*)d_in[1];
    const float* ema = (const float*)d_in[2];
    float* out = (float*)d_out;

    // ws: partial (64*16 tiles x 300 pairs f64 = 2,457,600 bytes)
    double* partial = (double*)d_ws;

    hipLaunchKernelGGL(proj_gram_kernel, dim3(512), dim3(128), 0, stream, x, w, partial);
    hipLaunchKernelGGL(eigh_feat_kernel, dim3(64), dim3(64), 0, stream, partial, ema, out);
}

// Round 11
// 407.127 us; speedup vs baseline: 1.0067x; 1.0067x over previous
//
#include <hip/hip_runtime.h>
#include <math.h>

// SVDObserver: x (64,512,64,64) f32, w_proj (24,512) f32, ema_s (24) f32
// outputs (flat f32 concat): S (64,24) | Vh (64,24,24) | features (64,50) | novelty (64,24)
//
//  K1 proj_gram: FROZEN (r10): 512 blk x 128 thr x 4 px, wave-private Gram,
//     fp64 partials. ~150 us (HBM floor 85 + Gram tail + staging).
//  K3 eigh_feat: r9/r10 structure + chase-chain surgery (all BIT-EXACT):
//     - next-iteration readlanes (e[i-1], d[i-1]) prefetched at loop top,
//       off the slartg dependent chain (write/read lanes proven disjoint)
//     - first chase iteration peeled (drops the i_!=mb+-1 guard)
//     - slartg range guard via min/max (exact same predicate)
//     - Z rotation uses  c*carry + s*prev / c*prev - s*carry  (IEEE-exact
//       rewrite of the sj=-s form)

#define N24 24
#define ZST 65  // Zl row stride: >=64 (rows 24-63 inert), odd (bank-friendly)
#define HS 25   // h staging pixel stride in K1

// ---------------------------------------------------------------- K1
__global__ __launch_bounds__(128, 1) void proj_gram_kernel(
    const float* __restrict__ x, const float* __restrict__ w,
    double* __restrict__ partial)
{
    const int b    = blockIdx.x >> 3;
    const int q    = blockIdx.x & 7;
    const int tid  = threadIdx.x;
    const int wv   = tid >> 6;
    const int lane = tid & 63;
    const int n0   = (q << 9) | (tid << 2);        // 4 consecutive pixels
    __shared__ __align__(16) float wl[24 * 512];   // 48 KB
    __shared__ float hq[2][64 * HS];               // 2 x 6.4 KB wave round-buffers
    for (int i2 = tid; i2 < 24 * 512; i2 += 128) wl[i2] = w[i2];
    __syncthreads();                               // the ONLY barrier

    const float* xb = x + ((size_t)b << 21) + n0;  // b*512*4096 + n0
    float h[4][24];
#pragma unroll
    for (int j = 0; j < 4; ++j)
#pragma unroll
        for (int k = 0; k < 24; ++k) h[j][k] = 0.f;

    float4 cA[8];
#pragma unroll
    for (int t = 0; t < 8; ++t)
        cA[t] = *reinterpret_cast<const float4*>(xb + ((size_t)t << 12));

    for (int c = 0; c < 512; c += 8) {
        float4 cB[8];
        if (c + 8 < 512) {
#pragma unroll
            for (int t = 0; t < 8; ++t)
                cB[t] = *reinterpret_cast<const float4*>(xb + ((size_t)(c + 8 + t) << 12));
        }
#pragma unroll
        for (int sub = 0; sub < 2; ++sub) {
            const float4 a0 = cA[sub * 4 + 0];
            const float4 a1 = cA[sub * 4 + 1];
            const float4 a2 = cA[sub * 4 + 2];
            const float4 a3 = cA[sub * 4 + 3];
            const int cc = c + sub * 4;
#pragma unroll
            for (int k = 0; k < 24; ++k) {
                const float4 wv4 = *reinterpret_cast<const float4*>(&wl[k * 512 + cc]);
                h[0][k] += wv4.x * a0.x + wv4.y * a1.x + wv4.z * a2.x + wv4.w * a3.x;
                h[1][k] += wv4.x * a0.y + wv4.y * a1.y + wv4.z * a2.y + wv4.w * a3.y;
                h[2][k] += wv4.x * a0.z + wv4.y * a1.z + wv4.z * a2.z + wv4.w * a3.z;
                h[3][k] += wv4.x * a0.w + wv4.y * a1.w + wv4.z * a2.w + wv4.w * a3.w;
            }
        }
#pragma unroll
        for (int t = 0; t < 8; ++t) cA[t] = cB[t];
    }

    // wave-private Gram over this wave's 256 px (tile = q*2+wv), 4 rounds of 64 px
    float* hr = hq[wv];
    int pk[5], pm[5];
#pragma unroll
    for (int u = 0; u < 5; ++u) {
        int p = lane + u * 64;
        int k = 0, pp = p;
        if (p < 300) {
            while (pp >= 24 - k) { pp -= 24 - k; ++k; }
        }
        pk[u] = k; pm[u] = k + pp;
    }
    double acc[5];
#pragma unroll
    for (int u = 0; u < 5; ++u) acc[u] = 0.0;

    for (int r = 0; r < 4; ++r) {
        if ((lane >> 4) == r) {                    // lanes 16r..16r+15 stage their 4 px
            int base = lane - (r << 4);            // 0..15
#pragma unroll
            for (int j = 0; j < 4; ++j)
#pragma unroll
                for (int k = 0; k < 24; ++k)
                    hr[((base << 2) + j) * HS + k] = h[j][k];
        }
        __builtin_amdgcn_wave_barrier();
#pragma unroll
        for (int u = 0; u < 5; ++u) {
            if (lane + u * 64 < 300) {
                double a = acc[u];
                for (int i2 = 0; i2 < 64; ++i2)
                    a += (double)hr[i2 * HS + pk[u]] * (double)hr[i2 * HS + pm[u]];
                acc[u] = a;
            }
        }
        __builtin_amdgcn_wave_barrier();
    }
#pragma unroll
    for (int u = 0; u < 5; ++u) {
        int p = lane + u * 64;
        if (p < 300)
            partial[((size_t)(b * 16 + (q << 1) + wv)) * 300 + p] = acc[u];
    }
}

// ------------------------------------------------------- LAPACK helpers
__device__ __forceinline__ float rlf(float v, int l) {
    return __int_as_float(__builtin_amdgcn_readlane(__float_as_int(v), l));
}

__device__ __forceinline__ float lapy2f(float xx, float yy) {
#pragma clang fp contract(off)
    float xa = fabsf(xx), ya = fabsf(yy);
    float w = fmaxf(xa, ya), z = fminf(xa, ya);
    float q = z / w;
    float res = w * sqrtf(1.f + q * q);
    return (z == 0.f) ? w : res;
}

// fast sqrt(g^2+1) via v_rsq (hot path only)
__device__ __forceinline__ float lapy2_1_fast(float g) {
    float t = g * g + 1.f;
    return t * __builtin_amdgcn_rsqf(t);
}

// hot-path slartg: v_rsq core. Guard predicate EXACTLY == r10's 4-term form.
__device__ __forceinline__ void slartg_(float f, float g, float& c, float& s, float& r) {
    float f1 = fabsf(f), g1 = fabsf(g);
    const float rtmin_ = 0x1p-63f;
    const float rtmax_ = 1.8446743e+19f;
    float mn = fminf(f1, g1), mx = fmaxf(f1, g1);
    bool inr = (mn > rtmin_) && (mx < rtmax_);
    if (__builtin_expect(!inr && f != 0.f && g != 0.f, 0)) {
#pragma clang fp contract(off)
        float u = fminf(3.4028235e+38f, fmaxf(0x1p-126f, mx));
        float fs = f / u, gs = g / u;
        float d = sqrtf(fs * fs + gs * gs);
        float p = 1.f / d;
        c = fabsf(fs) * p;
        s = gs * copysignf(p, f);
        r = copysignf(d, f) * u;
    } else {
        float d2 = f * f + g * g;
        float p = __builtin_amdgcn_rsqf(d2);
        float cN = f1 * p;
        float sN = g * copysignf(p, f);
        float rN = copysignf(d2 * p, f);
        bool gz = (g == 0.f);
        c = gz ? 1.f : cN;
        s = gz ? 0.f : sN;
        r = gz ? f : rN;
    }
}

__device__ __forceinline__ void slaev2_(float a, float b, float cc,
                                        float& rt1, float& rt2, float& cs1, float& sn1) {
#pragma clang fp contract(off)
    float sm = a + cc, df = a - cc, adf = fabsf(df);
    float tb = b + b, ab = fabsf(tb);
    float acmx, acmn;
    if (fabsf(a) > fabsf(cc)) { acmx = a; acmn = cc; } else { acmx = cc; acmn = a; }
    float rt;
    if (adf > ab)      { float q = ab / adf; rt = adf * sqrtf(1.f + q * q); }
    else if (adf < ab) { float q = adf / ab; rt = ab * sqrtf(1.f + q * q); }
    else               rt = ab * sqrtf(2.f);
    int sgn1;
    if (sm < 0.f)      { rt1 = 0.5f * (sm - rt); sgn1 = -1; rt2 = (acmx / rt1) * acmn - (b / rt1) * b; }
    else if (sm > 0.f) { rt1 = 0.5f * (sm + rt); sgn1 =  1; rt2 = (acmx / rt1) * acmn - (b / rt1) * b; }
    else               { rt1 = 0.5f * rt; rt2 = -0.5f * rt; sgn1 = 1; }
    float cs; int sgn2;
    if (df >= 0.f) { cs = df + rt; sgn2 = 1; } else { cs = df - rt; sgn2 = -1; }
    float acs = fabsf(cs);
    if (acs > ab) { float ct = -tb / cs; sn1 = 1.f / sqrtf(1.f + ct * ct); cs1 = ct * sn1; }
    else {
        if (ab == 0.f) { cs1 = 1.f; sn1 = 0.f; }
        else { float tn = -cs / tb; cs1 = 1.f / sqrtf(1.f + tn * tn); sn1 = tn * cs1; }
    }
    if (sgn1 == sgn2) { float tn = cs1; cs1 = -sn1; sn1 = tn; }
}

#define RD(j)   rlf(dr, (j) - 1)
#define RE(j)   rlf(er, (j) - 1)
#define WD(j,v) { float _v = (v); int _j = (j) - 1; dr = (lane == _j) ? _v : dr; }
#define WE(j,v) { float _v = (v); int _j = (j) - 1; er = (lane == _j) ? _v : er; }

// ---------------------------------------------------------------- K3 merged
__global__ __launch_bounds__(64) void eigh_feat_kernel(
    const double* __restrict__ partial, const float* __restrict__ ema,
    float* __restrict__ out)
{
#pragma clang fp contract(off)
    const int b = blockIdx.x;
    const int lane = threadIdx.x;
    const int n = N24;

    __shared__ float A[N24 * N24];      // col-major A[i + 24*j]
    __shared__ float Zl[ZST * N24];     // row r (0..63 incl. padding), col j at Zl[r + ZST*j]
    __shared__ float dl[N24 + 1], el[N24 + 1], tau[N24 + 1];
    __shared__ float hv[N24], hw[N24];
    __shared__ float Sarr[N24], snorm[N24];

    // ---------- G reduce prologue: 16 fp64 partials, serial t order ----------
    for (int p = lane; p < 300; p += 64) {
        int k = 0, pp = p;
        while (pp >= 24 - k) { pp -= 24 - k; ++k; }
        int m = k + pp;
        double acc = 0.0;
        for (int t = 0; t < 16; ++t)
            acc += partial[((size_t)(b * 16 + t)) * 300 + p];
        float v = (float)acc;
        A[k + N24 * m] = v;
        A[m + N24 * k] = v;
    }
    __syncthreads();

    // ---------- ssytd2 (lower) ----------
    for (int i = 0; i < n - 1; ++i) {
        const int mlen = n - 1 - i;
        float alpha = A[(i + 1) + N24 * i];
        float ss = 0.f;
        for (int r = i + 2; r < n; ++r) { float t = A[r + N24 * i]; ss += t * t; }
        float xnorm = sqrtf(ss);
        if (xnorm == 0.f) {
            if (lane == 0) { tau[i + 1] = 0.f; el[i + 1] = alpha; dl[i + 1] = A[i + N24 * i]; }
            __syncthreads();
            continue;
        }
        float beta = -copysignf(lapy2f(alpha, xnorm), alpha);
        float taui = (beta - alpha) / beta;
        float scal = 1.f / (alpha - beta);
        if (lane == 0) { tau[i + 1] = taui; el[i + 1] = beta; }
        __syncthreads();
        if (lane >= i + 2 && lane < n) A[lane + N24 * i] *= scal;
        __syncthreads();
        if (lane < mlen) hv[lane] = (lane == 0) ? 1.f : A[(i + 1 + lane) + N24 * i];
        __syncthreads();
        if (lane < mlen) {                      // x = tau * Asub * v
            float acc = 0.f;
            int gr = i + 1 + lane;
            for (int c2 = 0; c2 < mlen; ++c2) {
                int gc = i + 1 + c2;
                float av = (gr >= gc) ? A[gr + N24 * gc] : A[gc + N24 * gr];
                acc += av * hv[c2];
            }
            hw[lane] = taui * acc;
        }
        __syncthreads();
        float dot = 0.f;
        for (int r2 = 0; r2 < mlen; ++r2) dot += hw[r2] * hv[r2];
        float alpha2 = -0.5f * taui * dot;
        __syncthreads();
        if (lane < mlen) hw[lane] += alpha2 * hv[lane];
        __syncthreads();
        if (lane < mlen) {                      // rank-2 update, lower triangle
            for (int c2 = 0; c2 <= lane; ++c2)
                A[(i + 1 + lane) + N24 * (i + 1 + c2)] -= hv[lane] * hw[c2] + hw[lane] * hv[c2];
        }
        __syncthreads();
        if (lane == 0) dl[i + 1] = A[i + N24 * i];
        __syncthreads();
    }
    if (lane == 0) dl[n] = A[(n - 1) + N24 * (n - 1)];
    __syncthreads();

    // ---------- ssteqr('I'), Zl rows 24-63 are inert padding ----------
#pragma unroll
    for (int j = 0; j < N24; ++j) Zl[lane + ZST * j] = (lane == j) ? 1.f : 0.f;

    float dr = (lane < 24) ? dl[lane + 1] : 0.f;
    float er = (lane < 23) ? el[lane + 1] : 0.f;

    {
        const float eps_    = 0x1p-24f;
        const float eps2_   = 0x1p-48f;
        const float safmin_ = 0x1p-126f;
        const float ssfmax_ = 3.0744573e+18f;
        const float ssfmin_ = 0x1p-15f;
        const int nmaxit = n * 30;
        int jtot = 0, l1 = 1;
        int l = 0, lsv = 0, lend = 0, lendsv = 0, mb = 0, iscale = 0;
        float anorm = 0.f, p = 0.f, g = 0.f, r_ = 0.f, c_ = 0.f, s_ = 0.f, f_ = 0.f, b_ = 0.f;
        float rt1 = 0.f, rt2 = 0.f, cc = 0.f, sn = 0.f;
        int m_ = 0, i_ = 0;

L10:
        if (l1 > n) goto L160;
        if (l1 > 1) WE(l1 - 1, 0.f);
        {   // ballot deflation scan over m in [l1, n-1]
            float dnx = __shfl_down(dr, 1, 64);
            float ae = fabsf(er);
            bool inr = (lane >= l1 - 1) && (lane <= n - 2);
            bool t0 = inr && (ae == 0.f);
            bool t1 = inr && (ae <= (sqrtf(fabsf(dr)) * sqrtf(fabsf(dnx))) * eps_);
            unsigned long long msk0 = __ballot(t0);
            unsigned long long mskc = msk0 | __ballot(t1);
            if (mskc) {
                int bit = __builtin_ctzll(mskc);
                m_ = bit + 1;
                bool wasz = (msk0 >> bit) & 1ull;
                if (!wasz) WE(m_, 0.f);
            } else m_ = n;
        }
        l = l1; lsv = l; lend = m_; lendsv = lend; l1 = m_ + 1;
        if (lend == l) goto L10;

        {   // anorm (exact fmax reduce)
            bool ind = (lane >= l - 1) && (lane <= lend - 1);
            bool ine = (lane >= l - 1) && (lane <= lend - 2);
            float v = fmaxf(ind ? fabsf(dr) : 0.f, ine ? fabsf(er) : 0.f);
            for (int off = 32; off; off >>= 1) v = fmaxf(v, __shfl_xor(v, off, 64));
            anorm = v;
        }
        iscale = 0;
        if (anorm == 0.f) goto L10;
        if (anorm > ssfmax_) {
            iscale = 1;
            float mul = ssfmax_ / anorm;
            if (lane + 1 >= l && lane + 1 <= lend) dr *= mul;
            if (lane + 1 >= l && lane + 1 <= lend - 1) er *= mul;
        } else if (anorm < ssfmin_) {
            iscale = 2;
            float mul = ssfmin_ / anorm;
            if (lane + 1 >= l && lane + 1 <= lend) dr *= mul;
            if (lane + 1 >= l && lane + 1 <= lend - 1) er *= mul;
        }
        if (fabsf(RD(lend)) < fabsf(RD(l))) { lend = lsv; l = lendsv; }

        if (lend > l) {
            // ------------- QL -------------
L40:
            if (l != lend) {
                float dnx = __shfl_down(dr, 1, 64);
                bool inr = (lane >= l - 1) && (lane <= lend - 2);
                bool t = inr && (er * er <= (eps2_ * fabsf(dr)) * fabsf(dnx) + safmin_);
                unsigned long long msk = __ballot(t);
                m_ = msk ? (__builtin_ctzll(msk) + 1) : lend;
            } else m_ = lend;
            if (m_ < lend) WE(m_, 0.f);
            mb = m_;
            p = RD(l);
            if (mb == l) goto L80;
            if (mb == l + 1) {                      // 2x2 (unguarded: rows 24-63 inert)
                slaev2_(RD(l), RE(l), RD(l + 1), rt1, rt2, cc, sn);
                {
                    float z1 = Zl[lane + ZST * l];
                    float z0 = Zl[lane + ZST * (l - 1)];
                    Zl[lane + ZST * l]       = cc * z1 - sn * z0;
                    Zl[lane + ZST * (l - 1)] = sn * z1 + cc * z0;
                }
                WD(l, rt1); WD(l + 1, rt2); WE(l, 0.f);
                l = l + 2;
                if (l <= lend) goto L40;
                goto L140;
            }
            if (jtot == nmaxit) goto L140;
            jtot = jtot + 1;
            {
                float dmb = RD(mb);
                float el_ = RE(l);
                g = (RD(l + 1) - p) * __builtin_amdgcn_rcpf(2.f * el_);
                r_ = lapy2_1_fast(g);
                g = dmb - p + el_ * __builtin_amdgcn_rcpf(g + copysignf(r_, g));
                s_ = 1.f; c_ = 1.f; p = 0.f;
                float dcar = dmb;                   // d[i_+1] carry
                float carry = Zl[lane + ZST * (mb - 1)];
                // peeled first iteration i_ = mb-1 (no er write in original)
                i_ = mb - 1;
                float ei = RE(i_);
                float di = RD(i_);
                {
                    float prev = Zl[lane + ZST * (i_ - 1)];
                    int pidx = (i_ >= 2) ? (i_ - 2) : 0;
                    float nei = rlf(er, pidx);      // e[i_-1] prefetch (pre-chase lanes)
                    float ndi = rlf(dr, pidx);      // d[i_-1] prefetch
                    f_ = s_ * ei;
                    b_ = c_ * ei;
                    slartg_(g, f_, c_, s_, r_);
                    g = dcar - p;
                    r_ = (di - g) * s_ + 2.f * c_ * b_;
                    p = s_ * r_;
                    dr = (lane == i_) ? (g + p) : dr;              // WD(i_+1)
                    g = c_ * r_ - b_;
                    dcar = di;
                    Zl[lane + ZST * i_] = c_ * carry + s_ * prev;  // == c*carry - (-s)*prev
                    carry = c_ * prev - s_ * carry;                // == (-s)*carry + c*prev
                    ei = nei; di = ndi;
                }
                for (i_ = mb - 2; i_ >= l; --i_) {
                    float prev = Zl[lane + ZST * (i_ - 1)];
                    int pidx = (i_ >= 2) ? (i_ - 2) : 0;
                    float nei = rlf(er, pidx);
                    float ndi = rlf(dr, pidx);
                    f_ = s_ * ei;
                    b_ = c_ * ei;
                    slartg_(g, f_, c_, s_, r_);
                    er = (lane == i_) ? r_ : er;                   // WE(i_+1)
                    g = dcar - p;
                    r_ = (di - g) * s_ + 2.f * c_ * b_;
                    p = s_ * r_;
                    dr = (lane == i_) ? (g + p) : dr;              // WD(i_+1)
                    g = c_ * r_ - b_;
                    dcar = di;
                    Zl[lane + ZST * i_] = c_ * carry + s_ * prev;
                    carry = c_ * prev - s_ * carry;
                    ei = nei; di = ndi;
                }
                Zl[lane + ZST * (l - 1)] = carry;
                WD(l, dcar - p);
                WE(l, g);
            }
            goto L40;
L80:
            WD(l, p);
            l = l + 1;
            if (l <= lend) goto L40;
            goto L140;
        } else {
            // ------------- QR -------------
L90:
            if (l != lend) {
                float epu = __shfl_up(er, 1, 64);
                float dup = __shfl_up(dr, 1, 64);
                bool inr = (lane >= lend) && (lane <= l - 1);
                bool t = inr && (epu * epu <= (eps2_ * fabsf(dr)) * fabsf(dup) + safmin_);
                unsigned long long msk = __ballot(t);
                if (msk) {
                    m_ = 63 - __builtin_clzll(msk) + 1;
                } else m_ = lend;
            } else m_ = lend;
            if (m_ > lend) WE(m_ - 1, 0.f);
            mb = m_;
            p = RD(l);
            if (mb == l) goto L130;
            if (mb == l - 1) {                      // 2x2 (unguarded)
                slaev2_(RD(l - 1), RE(l - 1), RD(l), rt1, rt2, cc, sn);
                {
                    float z1 = Zl[lane + ZST * (l - 1)];
                    float z0 = Zl[lane + ZST * (l - 2)];
                    Zl[lane + ZST * (l - 1)] = cc * z1 - sn * z0;
                    Zl[lane + ZST * (l - 2)] = sn * z1 + cc * z0;
                }
                WD(l - 1, rt1); WD(l, rt2); WE(l - 1, 0.f);
                l = l - 2;
                if (l >= lend) goto L90;
                goto L140;
            }
            if (jtot == nmaxit) goto L140;
            jtot = jtot + 1;
            {
                float dmb = RD(mb);
                float el1 = RE(l - 1);
                g = (RD(l - 1) - p) * __builtin_amdgcn_rcpf(2.f * el1);
                r_ = lapy2_1_fast(g);
                g = dmb - p + el1 * __builtin_amdgcn_rcpf(g + copysignf(r_, g));
                s_ = 1.f; c_ = 1.f; p = 0.f;
                float dcar = dmb;                   // d[i_] carry
                float carryPrev = Zl[lane + ZST * (mb - 1)];
                // peeled first iteration i_ = mb (no er write in original)
                i_ = mb;
                float ei = RE(i_);
                float dnx = RD(i_ + 1);
                {
                    float t = Zl[lane + ZST * i_];
                    float nei = rlf(er, i_);        // RE(i_+1) = lane i_
                    float ndn = rlf(dr, i_ + 1);    // RD(i_+2) = lane i_+1
                    f_ = s_ * ei;
                    b_ = c_ * ei;
                    slartg_(g, f_, c_, s_, r_);
                    g = dcar - p;
                    r_ = (dnx - g) * s_ + 2.f * c_ * b_;
                    p = s_ * r_;
                    dr = (lane == i_ - 1) ? (g + p) : dr;          // WD(i_)
                    g = c_ * r_ - b_;
                    dcar = dnx;
                    Zl[lane + ZST * (i_ - 1)] = s_ * t + c_ * carryPrev;
                    carryPrev = c_ * t - s_ * carryPrev;
                    ei = nei; dnx = ndn;
                }
                for (i_ = mb + 1; i_ <= l - 1; ++i_) {
                    float t = Zl[lane + ZST * i_];
                    float nei = rlf(er, i_);
                    float ndn = rlf(dr, i_ + 1);
                    f_ = s_ * ei;
                    b_ = c_ * ei;
                    slartg_(g, f_, c_, s_, r_);
                    er = (lane == i_ - 2) ? r_ : er;               // WE(i_-1)
                    g = dcar - p;
                    r_ = (dnx - g) * s_ + 2.f * c_ * b_;
                    p = s_ * r_;
                    dr = (lane == i_ - 1) ? (g + p) : dr;          // WD(i_)
                    g = c_ * r_ - b_;
                    dcar = dnx;
                    Zl[lane + ZST * (i_ - 1)] = s_ * t + c_ * carryPrev;
                    carryPrev = c_ * t - s_ * carryPrev;
                    ei = nei; dnx = ndn;
                }
                Zl[lane + ZST * (l - 1)] = carryPrev;
                WD(l, dcar - p);
                WE(l - 1, g);
            }
            goto L90;
L130:
            WD(l, p);
            l = l - 1;
            if (l >= lend) goto L90;
            goto L140;
        }
L140:
        if (iscale == 1) {
            float mul = anorm / ssfmax_;
            if (lane + 1 >= lsv && lane + 1 <= lendsv) dr *= mul;
            if (lane + 1 >= lsv && lane + 1 <= lendsv - 1) er *= mul;
        } else if (iscale == 2) {
            float mul = anorm / ssfmin_;
            if (lane + 1 >= lsv && lane + 1 <= lendsv) dr *= mul;
            if (lane + 1 >= lsv && lane + 1 <= lendsv - 1) er *= mul;
        }
        if (jtot < nmaxit) goto L10;
        goto L160;

L160:
        // selection sort ascending via min+index reduce (tie -> lowest index)
        for (int ii = 2; ii <= n; ++ii) {
            int ia = ii - 1;
            float val = (lane >= ii - 2 && lane <= n - 1) ? dr : __builtin_inff();
            int idx = lane + 1;
            for (int off = 32; off; off >>= 1) {
                float v2 = __shfl_xor(val, off, 64);
                int   i2 = __shfl_xor(idx, off, 64);
                bool take = (v2 < val) || ((v2 == val) && (i2 < idx));
                val = take ? v2 : val;
                idx = take ? i2 : idx;
            }
            int ka = idx;
            float pp = val;
            if (ka != ia) {
                float dia = RD(ia);
                WD(ka, dia);
                WD(ia, pp);
                {   // unguarded column swap (rows 24-63 inert)
                    float t = Zl[lane + ZST * (ia - 1)];
                    Zl[lane + ZST * (ia - 1)] = Zl[lane + ZST * (ka - 1)];
                    Zl[lane + ZST * (ka - 1)] = t;
                }
            }
        }
    }

    if (lane < 24) dl[lane + 1] = dr;
    __syncthreads();

    // ---------- sormtr: Z := H(1)...H(n-1) * Z  (lane = column) ----------
    for (int i = n - 2; i >= 0; --i) {
        float taui = tau[i + 1];
        if (taui != 0.f && lane < n) {
            int j = lane;
            float w_ = Zl[(i + 1) + ZST * j];
            for (int r = i + 2; r < n; ++r) w_ += A[r + N24 * i] * Zl[r + ZST * j];
            Zl[(i + 1) + ZST * j] -= taui * w_;
            for (int r = i + 2; r < n; ++r) Zl[r + ZST * j] -= taui * (A[r + N24 * i] * w_);
        }
        __syncthreads();
    }

    // ---------- S, Vh, features, novelty ----------
    const int S_OFF = 0, VH_OFF = 1536, F_OFF = 38400, NOV_OFF = 41600;
    if (lane < n) {
        float ev = dl[n - lane];                   // descending
        float s0 = sqrtf(fmaxf(ev, 0.f));
        s0 = fmaxf(s0, 1e-6f);
        if (!isfinite(s0)) s0 = 1.f;
        Sarr[lane] = s0;
    }
    __syncthreads();
    if (lane < n) {
        out[S_OFF + b * 24 + lane] = Sarr[lane];
        out[NOV_OFF + b * 24 + lane] = Sarr[lane] - ema[lane];
    }
    for (int idx = lane; idx < 576; idx += 64) {   // Vh[j][i] = Z[i][23-j]
        int j = idx / 24, i2 = idx % 24;
        float vv = Zl[i2 + ZST * (23 - j)];
        if (!isfinite(vv)) vv = 0.f;
        out[VH_OFF + b * 576 + idx] = vv;
    }
    float sum_ = 0.f;
    for (int j2 = 0; j2 < n; ++j2) sum_ += Sarr[j2];
    float denom = sum_ + 1e-8f;
    if (lane < n) snorm[lane] = Sarr[lane] / denom;
    __syncthreads();
    float ent = 0.f;
    for (int j2 = 0; j2 < n; ++j2) {
        float sn2 = snorm[j2];
        ent -= sn2 * logf(fmaxf(sn2, 1e-8f));
    }
    float sumsq = 0.f, diagsq = 0.f;
    for (int j2 = 0; j2 < n; ++j2)
        for (int i2 = 0; i2 < n; ++i2) { float z = Zl[i2 + ZST * j2]; sumsq += z * z; }
    for (int j2 = 0; j2 < n; ++j2) { float dv = Zl[j2 + ZST * (23 - j2)]; diagsq += dv * dv; }
    float offd = fmaxf(sumsq - diagsq, 0.f);
    if (lane < n) {
        float v0 = snorm[lane]; if (!isfinite(v0)) v0 = 0.f;
        out[F_OFF + b * 50 + lane] = v0;
        float dv = Zl[lane + ZST * (23 - lane)]; if (!isfinite(dv)) dv = 0.f;
        out[F_OFF + b * 50 + 24 + lane] = dv;
    }
    if (lane == 0) {
        if (!isfinite(offd)) offd = 0.f;
        if (!isfinite(ent)) ent = 0.f;
        out[F_OFF + b * 50 + 48] = offd;
        out[F_OFF + b * 50 + 49] = ent;
    }
}

// ---------------------------------------------------------------- launch
extern "C" void kernel_launch(void* const* d_in, const int* in_sizes, int n_in,
                              void* d_out, int out_size, void* d_ws, size_t ws_size,
                              hipStream_t stream)
{
    const float* x   = (const float*)d_in[0];
    const float* w   = (const float*)d_in[1];
    const float* ema = (const float*)d_in[2];
    float* out = (float*)d_out;

    // ws: partial (64*16 tiles x 300 pairs f64 = 2,457,600 bytes)
    double* partial = (double*)d_ws;

    hipLaunchKernelGGL(proj_gram_kernel, dim3(512), dim3(128), 0, stream, x, w, partial);
    hipLaunchKernelGGL(eigh_feat_kernel, dim3(64), dim3(64), 0, stream, partial, ema, out);
}